// Round 8
// baseline (166.451 us; speedup 1.0000x reference)
//
#include <hip/hip_runtime.h>

// NetVLAD: N=16, C=1024, P=1024, K=32.
// k_prep (detect + W->bf16) -> k_attn (dbuf chunk tiles: x-transpose + W copy,
// MFMA logits, softmax; writes a~=a*rn bf16, asum fp32, xbf) -> k_vlad
// (dbuf chunk tiles: a~ + xbf pure copies, MFMA) -> factors -> out.
#define NB   16
#define CC   1024
#define PP   1024
#define KK   32
#define EPSF 1e-12f

typedef __attribute__((ext_vector_type(8))) short  bf16x8;
typedef __attribute__((ext_vector_type(4))) float  f32x4;
typedef unsigned short us;

__device__ __forceinline__ float bf2f(us u) {
    union { unsigned int i; float f; } v; v.i = ((unsigned int)u) << 16; return v.f;
}
__device__ __forceinline__ us f2bf(float f) {
    union { float f; unsigned int i; } v; v.f = f;
    return (us)((v.i + 0x7fffu + ((v.i >> 16) & 1u)) >> 16);  // RNE
}

template <typename T> struct IO;
template <> struct IO<float> {
    static __device__ __forceinline__ float  ld (const float* p) { return *p; }
    static __device__ __forceinline__ float4 ld4(const float* p) { return *(const float4*)p; }
};
template <> struct IO<us> {
    static __device__ __forceinline__ float  ld (const us* p) { return bf2f(*p); }
    static __device__ __forceinline__ float4 ld4(const us* p) {
        const ushort4 u = *(const ushort4*)p;
        return make_float4(bf2f(u.x), bf2f(u.y), bf2f(u.z), bf2f(u.w));
    }
};

// ---------------------------------------------------------------------------
// K0 (k_prep): grid 16. Per-block dtype detect (order-free); block 0 publishes
// flag; every block converts/copies its W slice to bf16.
// ---------------------------------------------------------------------------
__global__ __launch_bounds__(256) void k_prep(const us* __restrict__ xu,
                                              const void* __restrict__ w,
                                              int* __restrict__ flag,
                                              us* __restrict__ wbf) {
    __shared__ int s;
    const int b = blockIdx.x, t = threadIdx.x;
    if (t == 0) s = 0;
    __syncthreads();
    int bad = 0;
    for (int i = t; i < 4096; i += 256)
        if (((xu[i] >> 7) & 0xFFu) > 0x9Fu) bad = 1;
    if (bad) atomicOr(&s, 1);
    __syncthreads();
    const int f = s;
    if (b == 0 && t == 0) flag[0] = f;
    const int base = b * 2048 + t * 8;
    if (f) {
        const float* wf = (const float*)w;
        const float4 v0 = *(const float4*)(wf + base);
        const float4 v1 = *(const float4*)(wf + base + 4);
        ushort4 u0, u1;
        u0.x = f2bf(v0.x); u0.y = f2bf(v0.y); u0.z = f2bf(v0.z); u0.w = f2bf(v0.w);
        u1.x = f2bf(v1.x); u1.y = f2bf(v1.y); u1.z = f2bf(v1.z); u1.w = f2bf(v1.w);
        *(ushort4*)&wbf[base]     = u0;
        *(ushort4*)&wbf[base + 4] = u1;
    } else {
        *(uint4*)&wbf[base] = *(const uint4*)((const us*)w + base);
    }
}

// ---------------------------------------------------------------------------
// K1 (k_attn): per (n, 32px). Double-buffered chunk tiles xt/wc (8.7 KB each,
// ~35 KB total). One barrier per chunk: scatter(ch+1) into other buf while
// MFMA(ch) runs; global loads issued 2 chunks ahead. Epilogue: rnorm,
// softmax, a~ = a*rn bf16 + asum fp32 (+ xbf writeback during scatter).
// grid 512, block 256 (4 waves).
// ---------------------------------------------------------------------------
template <typename T, bool WRITE_XBF>
__device__ __forceinline__ void attn_body(const T* __restrict__ x,
                                          const us* __restrict__ wbf,
                                          us* __restrict__ xbf,
                                          us* __restrict__ attn_g,
                                          float* __restrict__ asum) {
    __shared__ __align__(16) us xt[2][32 * 136];   // [px][c-chunk]
    __shared__ __align__(16) us wc[2][32 * 136];   // [k][c-chunk]
    __shared__ float inv_lds[32];
    __shared__ float rn_lds[32];
    float* red = (float*)&xt[0][0];                // 32*33 f (post-loop reuse)
    float* lg  = red + 32 * 33;                    // 32*33 f

    const int b = blockIdx.x, t = threadIdx.x;
    const int n = b >> 5, pbase = (b & 31) * 32;
    const int lane = t & 63, wv = t >> 6;
    const int quad = lane >> 4, l15 = lane & 15;
    const int mt = wv >> 1, ntk = wv & 1;
    const int a = t & 7, crow = t >> 3, pxg = 4 * a;
    const int wrow = t >> 4, wcol8 = (t & 15) * 8; // W stage: rows 0..15 (s=0), 16..31 (s=1)
    const size_t xb = (size_t)n * CC * PP + pbase;

    float ss0 = 0.f, ss1 = 0.f, ss2 = 0.f, ss3 = 0.f;
    f32x4 acc = {0.f, 0.f, 0.f, 0.f};

    float4 xr[4];
    uint4 wr[2];

    // ---- preload + stage chunk 0 ----
    #pragma unroll
    for (int ps = 0; ps < 4; ++ps)
        xr[ps] = IO<T>::ld4(x + xb + (size_t)(crow + 32 * ps) * PP + pxg);
    #pragma unroll
    for (int s = 0; s < 2; ++s)
        wr[s] = *(const uint4*)&wbf[(wrow + 16 * s) * 1024 + wcol8];

    #pragma unroll
    for (int ps = 0; ps < 4; ++ps) {
        const float4 v = xr[ps];
        ss0 += v.x * v.x; ss1 += v.y * v.y; ss2 += v.z * v.z; ss3 += v.w * v.w;
        ushort4 u;
        u.x = f2bf(v.x); u.y = f2bf(v.y); u.z = f2bf(v.z); u.w = f2bf(v.w);
        const int cl = crow + 32 * ps;
        xt[0][(pxg + 0) * 136 + cl] = u.x;
        xt[0][(pxg + 1) * 136 + cl] = u.y;
        xt[0][(pxg + 2) * 136 + cl] = u.z;
        xt[0][(pxg + 3) * 136 + cl] = u.w;
        if (WRITE_XBF)
            *(ushort4*)&xbf[(size_t)(n * CC + cl) * PP + pbase + pxg] = u;
    }
    #pragma unroll
    for (int s = 0; s < 2; ++s)
        *(uint4*)&wc[0][(wrow + 16 * s) * 136 + wcol8] = wr[s];

    // ---- preload chunk 1 ----
    #pragma unroll
    for (int ps = 0; ps < 4; ++ps)
        xr[ps] = IO<T>::ld4(x + xb + (size_t)(128 + crow + 32 * ps) * PP + pxg);
    #pragma unroll
    for (int s = 0; s < 2; ++s)
        wr[s] = *(const uint4*)&wbf[(wrow + 16 * s) * 1024 + 128 + wcol8];

    __syncthreads();

    for (int ch = 0; ch < 8; ++ch) {
        const int cur = ch & 1, nxt = cur ^ 1;
        const int c0 = ch * 128;
        if (ch < 7) {
            const int c0n = c0 + 128;
            // stage chunk ch+1 into other buffer (concurrent with MFMA(ch))
            #pragma unroll
            for (int ps = 0; ps < 4; ++ps) {
                const float4 v = xr[ps];
                ss0 += v.x * v.x; ss1 += v.y * v.y; ss2 += v.z * v.z; ss3 += v.w * v.w;
                ushort4 u;
                u.x = f2bf(v.x); u.y = f2bf(v.y); u.z = f2bf(v.z); u.w = f2bf(v.w);
                const int cl = crow + 32 * ps;
                xt[nxt][(pxg + 0) * 136 + cl] = u.x;
                xt[nxt][(pxg + 1) * 136 + cl] = u.y;
                xt[nxt][(pxg + 2) * 136 + cl] = u.z;
                xt[nxt][(pxg + 3) * 136 + cl] = u.w;
                if (WRITE_XBF)
                    *(ushort4*)&xbf[(size_t)(n * CC + c0n + cl) * PP + pbase + pxg] = u;
            }
            #pragma unroll
            for (int s = 0; s < 2; ++s)
                *(uint4*)&wc[nxt][(wrow + 16 * s) * 136 + wcol8] = wr[s];
        }
        if (ch < 6) {
            const int c0nn = c0 + 256;
            #pragma unroll
            for (int ps = 0; ps < 4; ++ps)
                xr[ps] = IO<T>::ld4(x + xb + (size_t)(c0nn + crow + 32 * ps) * PP + pxg);
            #pragma unroll
            for (int s = 0; s < 2; ++s)
                wr[s] = *(const uint4*)&wbf[(wrow + 16 * s) * 1024 + c0nn + wcol8];
        }
        #pragma unroll
        for (int ks = 0; ks < 4; ++ks) {
            const bf16x8 av = *(const bf16x8*)&xt[cur][(mt * 16 + l15) * 136 + ks * 32 + quad * 8];
            const bf16x8 bv = *(const bf16x8*)&wc[cur][(ntk * 16 + l15) * 136 + ks * 32 + quad * 8];
            acc = __builtin_amdgcn_mfma_f32_16x16x32_bf16(av, bv, acc, 0, 0, 0);
        }
        __syncthreads();
    }
    // ---- epilogue: rnorm -> softmax -> a~/asum ----
    red[crow * 33 + pxg + 0] = ss0;
    red[crow * 33 + pxg + 1] = ss1;
    red[crow * 33 + pxg + 2] = ss2;
    red[crow * 33 + pxg + 3] = ss3;
    __syncthreads();
    if (t < 32) {
        float s = 0.f;
        #pragma unroll
        for (int g = 0; g < 32; ++g) s += red[g * 33 + t];
        rn_lds[t] = 1.0f / fmaxf(sqrtf(s), EPSF);
    }
    __syncthreads();
    #pragma unroll
    for (int reg = 0; reg < 4; ++reg) {
        const int px = mt * 16 + quad * 4 + reg;
        lg[px * 33 + ntk * 16 + l15] = acc[reg] * rn_lds[px];
    }
    __syncthreads();
    if (t < 32) {
        float m = -1e30f;
        #pragma unroll
        for (int k = 0; k < KK; ++k) m = fmaxf(m, lg[t * 33 + k]);
        float s = 0.f;
        #pragma unroll
        for (int k = 0; k < KK; ++k) {
            const float e = expf(lg[t * 33 + k] - m);
            lg[t * 33 + k] = e;
            s += e;
        }
        inv_lds[t] = 1.0f / s;
    }
    __syncthreads();
    {
        const int k = t >> 3, ps2 = (t & 7) * 4;
        ushort4 u;
        float sum = 0.f;
        #pragma unroll
        for (int j = 0; j < 4; ++j) {
            const int px = ps2 + j;
            const float e = lg[px * 33 + k] * inv_lds[px];   // a (fp32)
            sum += e;
            ((us*)&u)[j] = f2bf(e * rn_lds[px]);             // a~ bf16
        }
        *(ushort4*)&attn_g[((size_t)n * KK + k) * PP + pbase + ps2] = u;
        sum += __shfl_down(sum, 1, 64);
        sum += __shfl_down(sum, 2, 64);
        sum += __shfl_down(sum, 4, 64);
        if ((t & 7) == 0) atomicAdd(&asum[n * KK + k], sum);
    }
}
__global__ __launch_bounds__(256) void k_attn(const void* __restrict__ x,
                                              const us* __restrict__ wbf,
                                              const int* __restrict__ flag,
                                              us* __restrict__ xbf,
                                              us* __restrict__ attn_g,
                                              float* __restrict__ asum) {
    if (*flag) attn_body<float, true>((const float*)x, wbf, xbf, attn_g, asum);
    else       attn_body<us, false>((const us*)x, wbf, xbf, attn_g, asum);
}

// ---------------------------------------------------------------------------
// K2 (k_vlad): per (n, 32c). Double-buffered chunk tiles ac/xc (pure uint4
// copies; a~ is 1 MB L2-hot, xbf 32 MB). Same one-barrier-per-chunk pipeline.
// Epilogue: -asum*cent, fp32 store, ssq atomics. grid 512, block 256.
// ---------------------------------------------------------------------------
template <typename T>
__device__ __forceinline__ void vlad_body(const us* __restrict__ xsrc,
                                          const us* __restrict__ attn_g,
                                          const T* __restrict__ cent,
                                          const float* __restrict__ asum,
                                          float* __restrict__ vlad,
                                          float* __restrict__ ssqnk) {
    __shared__ __align__(16) us ac[2][32 * 136];   // [k][p-chunk]
    __shared__ __align__(16) us xc[2][32 * 136];   // [c-local][p-chunk]
    __shared__ float asum_lds[32];
    const int b = blockIdx.x, t = threadIdx.x;
    const int n = b >> 5, cb = (b & 31) * 32;
    const int lane = t & 63, wv = t >> 6;
    const int quad = lane >> 4, l15 = lane & 15;
    const int mtk = wv >> 1, ntc = wv & 1;
    const int row = t >> 4, col8 = (t & 15) * 8;   // staging: rows r, r+16

    if (t < 32) asum_lds[t] = asum[n * KK + t];

    f32x4 acc = {0.f, 0.f, 0.f, 0.f};
    const size_t xb = ((size_t)n * CC + cb) * PP;
    const size_t ab = (size_t)n * KK * PP;

    uint4 ar[2], xr[2];
    // preload + stage chunk 0
    #pragma unroll
    for (int s = 0; s < 2; ++s) {
        ar[s] = *(const uint4*)&attn_g[ab + (size_t)(row + 16 * s) * PP + col8];
        xr[s] = *(const uint4*)&xsrc[xb + (size_t)(row + 16 * s) * PP + col8];
    }
    #pragma unroll
    for (int s = 0; s < 2; ++s) {
        *(uint4*)&ac[0][(row + 16 * s) * 136 + col8] = ar[s];
        *(uint4*)&xc[0][(row + 16 * s) * 136 + col8] = xr[s];
    }
    // preload chunk 1
    #pragma unroll
    for (int s = 0; s < 2; ++s) {
        ar[s] = *(const uint4*)&attn_g[ab + (size_t)(row + 16 * s) * PP + 128 + col8];
        xr[s] = *(const uint4*)&xsrc[xb + (size_t)(row + 16 * s) * PP + 128 + col8];
    }
    __syncthreads();

    for (int ch = 0; ch < 8; ++ch) {
        const int cur = ch & 1, nxt = cur ^ 1;
        const int p0 = ch * 128;
        if (ch < 7) {
            #pragma unroll
            for (int s = 0; s < 2; ++s) {
                *(uint4*)&ac[nxt][(row + 16 * s) * 136 + col8] = ar[s];
                *(uint4*)&xc[nxt][(row + 16 * s) * 136 + col8] = xr[s];
            }
        }
        if (ch < 6) {
            const int p0nn = p0 + 256;
            #pragma unroll
            for (int s = 0; s < 2; ++s) {
                ar[s] = *(const uint4*)&attn_g[ab + (size_t)(row + 16 * s) * PP + p0nn + col8];
                xr[s] = *(const uint4*)&xsrc[xb + (size_t)(row + 16 * s) * PP + p0nn + col8];
            }
        }
        #pragma unroll
        for (int ks = 0; ks < 4; ++ks) {
            const bf16x8 av = *(const bf16x8*)&ac[cur][(mtk * 16 + l15) * 136 + ks * 32 + quad * 8];
            const bf16x8 bv = *(const bf16x8*)&xc[cur][(ntc * 16 + l15) * 136 + ks * 32 + quad * 8];
            acc = __builtin_amdgcn_mfma_f32_16x16x32_bf16(av, bv, acc, 0, 0, 0);
        }
        __syncthreads();
    }
    // D: row(k)=quad*4+reg (+mtk*16), col(c)=l15 (+ntc*16)
    const int cg = cb + ntc * 16 + l15;
    #pragma unroll
    for (int reg = 0; reg < 4; ++reg) {
        const int k = mtk * 16 + quad * 4 + reg;
        const float A = asum_lds[k];
        const float v = acc[reg] - A * IO<T>::ld(&cent[k * CC + cg]);
        vlad[((size_t)n * KK + k) * CC + cg] = v;
        float s = v * v;
        s += __shfl_xor(s, 1, 64);
        s += __shfl_xor(s, 2, 64);
        s += __shfl_xor(s, 4, 64);
        s += __shfl_xor(s, 8, 64);
        if (l15 == 0) atomicAdd(&ssqnk[n * KK + k], s);
    }
}
__global__ __launch_bounds__(256) void k_vlad(const void* __restrict__ x,
                                              const us* __restrict__ xbf,
                                              const us* __restrict__ attn_g,
                                              const void* __restrict__ cent,
                                              const int* __restrict__ flag,
                                              const float* __restrict__ asum,
                                              float* __restrict__ vlad,
                                              float* __restrict__ ssqnk) {
    if (*flag) vlad_body<float>(xbf, attn_g, (const float*)cent, asum, vlad, ssqnk);
    else       vlad_body<us>((const us*)x, attn_g, (const us*)cent, asum, vlad, ssqnk);
}

// ---------------------------------------------------------------------------
// K3: per (n,k) intra rnorm; per n global rnorm (sum_k ssq_k * r_k^2).
// ---------------------------------------------------------------------------
__global__ __launch_bounds__(64) void k_factors(const float* __restrict__ ssqnk,
                                                float* __restrict__ rintra,
                                                float* __restrict__ rglob) {
    const int n = blockIdx.x, t = threadIdx.x;
    const float s = (t < KK) ? ssqnk[n * KK + t] : 0.f;
    const float r = 1.0f / fmaxf(sqrtf(s), EPSF);
    if (t < KK) rintra[n * KK + t] = r;
    float g = s * r * r;
    for (int off = 32; off > 0; off >>= 1) g += __shfl_down(g, off, 64);
    if (t == 0) rglob[n] = 1.0f / fmaxf(sqrtf(g), EPSF);
}

// ---------------------------------------------------------------------------
// K4: out = vlad * rintra * rglob. grid N*K, 256 thr (float4 per thread).
// ---------------------------------------------------------------------------
__global__ __launch_bounds__(256) void k_out(const float* __restrict__ vlad,
                                             const float* __restrict__ rintra,
                                             const float* __restrict__ rglob,
                                             const int* __restrict__ flag,
                                             void* __restrict__ out) {
    const int b = blockIdx.x, t = threadIdx.x;
    const float f = rintra[b] * rglob[b >> 5];
    const float4 v = ((const float4*)(vlad + (size_t)b * CC))[t];
    if (*flag) {
        float4 o; o.x = v.x * f; o.y = v.y * f; o.z = v.z * f; o.w = v.w * f;
        ((float4*)((float*)out + (size_t)b * CC))[t] = o;
    } else {
        ushort4 u;
        u.x = f2bf(v.x * f); u.y = f2bf(v.y * f);
        u.z = f2bf(v.z * f); u.w = f2bf(v.w * f);
        ((ushort4*)((us*)out + (size_t)b * CC))[t] = u;
    }
}

extern "C" void kernel_launch(void* const* d_in, const int* in_sizes, int n_in,
                              void* d_out, int out_size, void* d_ws, size_t ws_size,
                              hipStream_t stream) {
    const void* x    = d_in[0];
    const void* w    = d_in[1];
    const void* cent = d_in[2];

    float* ws     = (float*)d_ws;
    float* vlad   = ws;                       // 524288 f
    float* asum   = vlad + 524288;            // 512 f
    float* ssqnk  = asum + 512;               // 512 f
    float* rintra = ssqnk + 512;              // 512 f
    float* rglob  = rintra + 512;             // 16 f
    int*   flag   = (int*)(rglob + 16);       // 4 i
    us* attn_g = (us*)(flag + 4);             // 524288 us  (a~ = a*rn, bf16)
    us* xbf    = attn_g + 524288;             // 16777216 us (bf16(x) raw)
    us* wbf    = xbf + 16777216;              // 32768 us

    hipMemsetAsync(asum, 0, 2 * NB * KK * sizeof(float), stream);  // asum+ssqnk

    k_prep<<<16, 256, 0, stream>>>((const us*)x, w, flag, wbf);
    k_attn<<<NB * 32, 256, 0, stream>>>(x, wbf, flag, xbf, attn_g, asum);
    k_vlad<<<NB * 32, 256, 0, stream>>>(x, xbf, attn_g, cent, flag, asum, vlad, ssqnk);
    k_factors<<<NB, 64, 0, stream>>>(ssqnk, rintra, rglob);
    k_out<<<NB * KK, 256, 0, stream>>>(vlad, rintra, rglob, flag, d_out);
}

// Round 9
// 148.641 us; speedup vs baseline: 1.1198x; 1.1198x over previous
//
#include <hip/hip_runtime.h>

// NetVLAD: N=16, C=1024, P=1024, K=32.
// prep -> k_attn (c-split halves, partial logits+ssq) -> k_soft (reduce+softmax,
// emits a~=a*rn bf16 + asum) -> k_vlad (p-split halves, partial sums) ->
// k_vfin (combine, -A*cent, ssq) -> k_factors -> k_out.
#define NB   16
#define CC   1024
#define PP   1024
#define KK   32
#define EPSF 1e-12f

typedef __attribute__((ext_vector_type(8))) short  bf16x8;
typedef __attribute__((ext_vector_type(4))) float  f32x4;
typedef unsigned short us;

__device__ __forceinline__ float bf2f(us u) {
    union { unsigned int i; float f; } v; v.i = ((unsigned int)u) << 16; return v.f;
}
__device__ __forceinline__ us f2bf(float f) {
    union { float f; unsigned int i; } v; v.f = f;
    return (us)((v.i + 0x7fffu + ((v.i >> 16) & 1u)) >> 16);  // RNE
}

template <typename T> struct IO;
template <> struct IO<float> {
    static __device__ __forceinline__ float  ld (const float* p) { return *p; }
    static __device__ __forceinline__ float4 ld4(const float* p) { return *(const float4*)p; }
};
template <> struct IO<us> {
    static __device__ __forceinline__ float  ld (const us* p) { return bf2f(*p); }
    static __device__ __forceinline__ float4 ld4(const us* p) {
        const ushort4 u = *(const ushort4*)p;
        return make_float4(bf2f(u.x), bf2f(u.y), bf2f(u.z), bf2f(u.w));
    }
};

// ---------------------------------------------------------------------------
// K0 (k_prep): grid 16. Per-block dtype detect; block 0 publishes flag;
// every block converts/copies its W slice to bf16.
// ---------------------------------------------------------------------------
__global__ __launch_bounds__(256) void k_prep(const us* __restrict__ xu,
                                              const void* __restrict__ w,
                                              int* __restrict__ flag,
                                              us* __restrict__ wbf) {
    __shared__ int s;
    const int b = blockIdx.x, t = threadIdx.x;
    if (t == 0) s = 0;
    __syncthreads();
    int bad = 0;
    for (int i = t; i < 4096; i += 256)
        if (((xu[i] >> 7) & 0xFFu) > 0x9Fu) bad = 1;
    if (bad) atomicOr(&s, 1);
    __syncthreads();
    const int f = s;
    if (b == 0 && t == 0) flag[0] = f;
    const int base = b * 2048 + t * 8;
    if (f) {
        const float* wf = (const float*)w;
        const float4 v0 = *(const float4*)(wf + base);
        const float4 v1 = *(const float4*)(wf + base + 4);
        ushort4 u0, u1;
        u0.x = f2bf(v0.x); u0.y = f2bf(v0.y); u0.z = f2bf(v0.z); u0.w = f2bf(v0.w);
        u1.x = f2bf(v1.x); u1.y = f2bf(v1.y); u1.z = f2bf(v1.z); u1.w = f2bf(v1.w);
        *(ushort4*)&wbf[base]     = u0;
        *(ushort4*)&wbf[base + 4] = u1;
    } else {
        *(uint4*)&wbf[base] = *(const uint4*)((const us*)w + base);
    }
}

// ---------------------------------------------------------------------------
// K1 (k_attn): grid 1024 = n*64 + pt*2 + h. Block handles (n, 32px, c-half
// of 512). Dbuf chunk tiles (4x4352 us = 34 KB shared across dtype paths).
// Stores partial MFMA acc (float4/thread) + partial sumsq (32/block) to ws.
// ---------------------------------------------------------------------------
template <typename T>
__device__ __forceinline__ void attn_body(const T* __restrict__ x,
                                          const us* __restrict__ wbf,
                                          float* __restrict__ part,
                                          float* __restrict__ ssp,
                                          us* sm) {
    const int b = blockIdx.x, t = threadIdx.x;
    const int n = b >> 6, pt = (b >> 1) & 31, h = b & 1;
    const int pbase = pt * 32, cbase = h * 512;
    const int lane = t & 63, wv = t >> 6;
    const int quad = lane >> 4, l15 = lane & 15;
    const int mt = wv >> 1, ntk = wv & 1;
    const int a = t & 7, crow = t >> 3, pxg = 4 * a;
    const int wrow = t >> 4, wcol8 = (t & 15) * 8;
    const size_t xb = (size_t)n * CC * PP + pbase;
    us* xt0 = sm;            us* xt1 = sm + 4352;
    us* wc0 = sm + 8704;     us* wc1 = sm + 13056;

    float ss0 = 0.f, ss1 = 0.f, ss2 = 0.f, ss3 = 0.f;
    f32x4 acc = {0.f, 0.f, 0.f, 0.f};
    float4 xr[4];
    uint4 wr[2];

    // chunk 0 load + stage
    #pragma unroll
    for (int ps = 0; ps < 4; ++ps)
        xr[ps] = IO<T>::ld4(x + xb + (size_t)(cbase + crow + 32 * ps) * PP + pxg);
    #pragma unroll
    for (int s = 0; s < 2; ++s)
        wr[s] = *(const uint4*)&wbf[(wrow + 16 * s) * 1024 + cbase + wcol8];
    #pragma unroll
    for (int ps = 0; ps < 4; ++ps) {
        const float4 v = xr[ps];
        ss0 += v.x * v.x; ss1 += v.y * v.y; ss2 += v.z * v.z; ss3 += v.w * v.w;
        const int cl = crow + 32 * ps;
        xt0[(pxg + 0) * 136 + cl] = f2bf(v.x);
        xt0[(pxg + 1) * 136 + cl] = f2bf(v.y);
        xt0[(pxg + 2) * 136 + cl] = f2bf(v.z);
        xt0[(pxg + 3) * 136 + cl] = f2bf(v.w);
    }
    #pragma unroll
    for (int s = 0; s < 2; ++s)
        *(uint4*)&wc0[(wrow + 16 * s) * 136 + wcol8] = wr[s];
    // chunk 1 load
    #pragma unroll
    for (int ps = 0; ps < 4; ++ps)
        xr[ps] = IO<T>::ld4(x + xb + (size_t)(cbase + 128 + crow + 32 * ps) * PP + pxg);
    #pragma unroll
    for (int s = 0; s < 2; ++s)
        wr[s] = *(const uint4*)&wbf[(wrow + 16 * s) * 1024 + cbase + 128 + wcol8];
    __syncthreads();

    for (int ch = 0; ch < 4; ++ch) {
        const int cur = ch & 1;
        us* xtc = cur ? xt1 : xt0;
        us* wcc = cur ? wc1 : wc0;
        us* xtn = cur ? xt0 : xt1;
        us* wcn = cur ? wc0 : wc1;
        if (ch < 3) {
            #pragma unroll
            for (int ps = 0; ps < 4; ++ps) {
                const float4 v = xr[ps];
                ss0 += v.x * v.x; ss1 += v.y * v.y; ss2 += v.z * v.z; ss3 += v.w * v.w;
                const int cl = crow + 32 * ps;
                xtn[(pxg + 0) * 136 + cl] = f2bf(v.x);
                xtn[(pxg + 1) * 136 + cl] = f2bf(v.y);
                xtn[(pxg + 2) * 136 + cl] = f2bf(v.z);
                xtn[(pxg + 3) * 136 + cl] = f2bf(v.w);
            }
            #pragma unroll
            for (int s = 0; s < 2; ++s)
                *(uint4*)&wcn[(wrow + 16 * s) * 136 + wcol8] = wr[s];
        }
        if (ch < 2) {
            const int c0nn = cbase + (ch + 2) * 128;
            #pragma unroll
            for (int ps = 0; ps < 4; ++ps)
                xr[ps] = IO<T>::ld4(x + xb + (size_t)(c0nn + crow + 32 * ps) * PP + pxg);
            #pragma unroll
            for (int s = 0; s < 2; ++s)
                wr[s] = *(const uint4*)&wbf[(wrow + 16 * s) * 1024 + c0nn + wcol8];
        }
        #pragma unroll
        for (int ks = 0; ks < 4; ++ks) {
            const bf16x8 av = *(const bf16x8*)&xtc[(mt * 16 + l15) * 136 + ks * 32 + quad * 8];
            const bf16x8 bv = *(const bf16x8*)&wcc[(ntk * 16 + l15) * 136 + ks * 32 + quad * 8];
            acc = __builtin_amdgcn_mfma_f32_16x16x32_bf16(av, bv, acc, 0, 0, 0);
        }
        __syncthreads();
    }
    // store partial acc
    *(float4*)&part[(size_t)b * 1024 + t * 4] =
        make_float4(acc[0], acc[1], acc[2], acc[3]);
    // partial sumsq reduce (reuse sm as float red[32*33])
    float* red = (float*)sm;
    red[crow * 33 + pxg + 0] = ss0;
    red[crow * 33 + pxg + 1] = ss1;
    red[crow * 33 + pxg + 2] = ss2;
    red[crow * 33 + pxg + 3] = ss3;
    __syncthreads();
    if (t < 32) {
        float s = 0.f;
        #pragma unroll
        for (int g = 0; g < 32; ++g) s += red[g * 33 + t];
        ssp[b * 32 + t] = s;
    }
}
__global__ __launch_bounds__(256) void k_attn(const void* __restrict__ x,
                                              const us* __restrict__ wbf,
                                              const int* __restrict__ flag,
                                              float* __restrict__ part,
                                              float* __restrict__ ssp) {
    __shared__ __align__(16) us sm[4 * 4352];
    if (*flag) attn_body<float>((const float*)x, wbf, part, ssp, sm);
    else       attn_body<us>((const us*)x, wbf, part, ssp, sm);
}

// ---------------------------------------------------------------------------
// K2 (k_soft): grid 512 = n*32 + pt. Combine the two c-halves' partial logits
// + sumsq, rnorm-scale, softmax over k, write a~ = a*rn (bf16) + asum (fp32).
// ---------------------------------------------------------------------------
__global__ __launch_bounds__(256) void k_soft(const float* __restrict__ part,
                                              const float* __restrict__ ssp,
                                              us* __restrict__ attn_g,
                                              float* __restrict__ asum) {
    __shared__ float lg[32 * 33];
    __shared__ float rn_lds[32], inv_lds[32];
    const int s = blockIdx.x, t = threadIdx.x;
    const int n = s >> 5, pt = s & 31, pbase = pt * 32;
    const int b0 = n * 64 + pt * 2, b1 = b0 + 1;
    const float4 f0 = *(const float4*)&part[(size_t)b0 * 1024 + t * 4];
    const float4 f1 = *(const float4*)&part[(size_t)b1 * 1024 + t * 4];
    if (t < 32) {
        const float ssq = ssp[b0 * 32 + t] + ssp[b1 * 32 + t];
        rn_lds[t] = 1.0f / fmaxf(sqrtf(ssq), EPSF);
    }
    __syncthreads();
    const int lane = t & 63, wv = t >> 6;
    const int quad = lane >> 4, l15 = lane & 15;
    const int mt = wv >> 1, ntk = wv & 1;
    const float vals[4] = {f0.x + f1.x, f0.y + f1.y, f0.z + f1.z, f0.w + f1.w};
    #pragma unroll
    for (int reg = 0; reg < 4; ++reg) {
        const int px = mt * 16 + quad * 4 + reg;
        lg[px * 33 + ntk * 16 + l15] = vals[reg] * rn_lds[px];
    }
    __syncthreads();
    if (t < 32) {
        float m = -1e30f;
        #pragma unroll
        for (int k = 0; k < KK; ++k) m = fmaxf(m, lg[t * 33 + k]);
        float sm2 = 0.f;
        #pragma unroll
        for (int k = 0; k < KK; ++k) {
            const float e = expf(lg[t * 33 + k] - m);
            lg[t * 33 + k] = e;
            sm2 += e;
        }
        inv_lds[t] = 1.0f / sm2;
    }
    __syncthreads();
    {
        const int k = t >> 3, ps2 = (t & 7) * 4;
        ushort4 u;
        float sum = 0.f;
        #pragma unroll
        for (int j = 0; j < 4; ++j) {
            const int px = ps2 + j;
            const float e = lg[px * 33 + k] * inv_lds[px];   // a (fp32)
            sum += e;
            ((us*)&u)[j] = f2bf(e * rn_lds[px]);             // a~ = a*rn bf16
        }
        *(ushort4*)&attn_g[((size_t)n * KK + k) * PP + pbase + ps2] = u;
        sum += __shfl_down(sum, 1, 64);
        sum += __shfl_down(sum, 2, 64);
        sum += __shfl_down(sum, 4, 64);
        if ((t & 7) == 0) atomicAdd(&asum[n * KK + k], sum);
    }
}

// ---------------------------------------------------------------------------
// K3 (k_vlad): grid 1024 = n*64 + ct*2 + h. Block: (n, 32c, p-half of 512).
// vlad_part = a~ @ x_raw^T over its p-half. a~ copied, x converted in staging.
// Stores partial acc (float4/thread) to ws.
// ---------------------------------------------------------------------------
template <typename T>
__device__ __forceinline__ void vlad_body(const T* __restrict__ x,
                                          const us* __restrict__ attn_g,
                                          float* __restrict__ partv,
                                          us* sm) {
    const int b = blockIdx.x, t = threadIdx.x;
    const int n = b >> 6, ct = (b >> 1) & 31, h = b & 1;
    const int cb = ct * 32, pb = h * 512;
    const int lane = t & 63, wv = t >> 6;
    const int quad = lane >> 4, l15 = lane & 15;
    const int mtk = wv >> 1, ntc = wv & 1;
    const int row = t >> 4, col8 = (t & 15) * 8;
    us* ac0 = sm;            us* ac1 = sm + 4352;
    us* xc0 = sm + 8704;     us* xc1 = sm + 13056;

    f32x4 acc = {0.f, 0.f, 0.f, 0.f};
    const size_t xb = ((size_t)n * CC + cb) * PP + pb;
    const size_t ab = (size_t)n * KK * PP + pb;

    uint4 ar[2];
    float4 xf[4];

    // chunk 0 load + stage
    #pragma unroll
    for (int s = 0; s < 2; ++s) {
        ar[s]         = *(const uint4*)&attn_g[ab + (size_t)(row + 16 * s) * PP + col8];
        xf[2 * s]     = IO<T>::ld4(x + xb + (size_t)(row + 16 * s) * PP + col8);
        xf[2 * s + 1] = IO<T>::ld4(x + xb + (size_t)(row + 16 * s) * PP + col8 + 4);
    }
    #pragma unroll
    for (int s = 0; s < 2; ++s) {
        *(uint4*)&ac0[(row + 16 * s) * 136 + col8] = ar[s];
        ushort4 u0, u1;
        const float4 v0 = xf[2 * s], v1 = xf[2 * s + 1];
        u0.x = f2bf(v0.x); u0.y = f2bf(v0.y); u0.z = f2bf(v0.z); u0.w = f2bf(v0.w);
        u1.x = f2bf(v1.x); u1.y = f2bf(v1.y); u1.z = f2bf(v1.z); u1.w = f2bf(v1.w);
        *(ushort4*)&xc0[(row + 16 * s) * 136 + col8]     = u0;
        *(ushort4*)&xc0[(row + 16 * s) * 136 + col8 + 4] = u1;
    }
    // chunk 1 load
    #pragma unroll
    for (int s = 0; s < 2; ++s) {
        ar[s]         = *(const uint4*)&attn_g[ab + (size_t)(row + 16 * s) * PP + 128 + col8];
        xf[2 * s]     = IO<T>::ld4(x + xb + (size_t)(row + 16 * s) * PP + 128 + col8);
        xf[2 * s + 1] = IO<T>::ld4(x + xb + (size_t)(row + 16 * s) * PP + 128 + col8 + 4);
    }
    __syncthreads();

    for (int ch = 0; ch < 4; ++ch) {
        const int cur = ch & 1;
        us* acc_ = cur ? ac1 : ac0;
        us* xcc  = cur ? xc1 : xc0;
        us* acn  = cur ? ac0 : ac1;
        us* xcn  = cur ? xc0 : xc1;
        if (ch < 3) {
            #pragma unroll
            for (int s = 0; s < 2; ++s) {
                *(uint4*)&acn[(row + 16 * s) * 136 + col8] = ar[s];
                ushort4 u0, u1;
                const float4 v0 = xf[2 * s], v1 = xf[2 * s + 1];
                u0.x = f2bf(v0.x); u0.y = f2bf(v0.y); u0.z = f2bf(v0.z); u0.w = f2bf(v0.w);
                u1.x = f2bf(v1.x); u1.y = f2bf(v1.y); u1.z = f2bf(v1.z); u1.w = f2bf(v1.w);
                *(ushort4*)&xcn[(row + 16 * s) * 136 + col8]     = u0;
                *(ushort4*)&xcn[(row + 16 * s) * 136 + col8 + 4] = u1;
            }
        }
        if (ch < 2) {
            const int p0nn = (ch + 2) * 128;
            #pragma unroll
            for (int s = 0; s < 2; ++s) {
                ar[s]         = *(const uint4*)&attn_g[ab + (size_t)(row + 16 * s) * PP + p0nn + col8];
                xf[2 * s]     = IO<T>::ld4(x + xb + (size_t)(row + 16 * s) * PP + p0nn + col8);
                xf[2 * s + 1] = IO<T>::ld4(x + xb + (size_t)(row + 16 * s) * PP + p0nn + col8 + 4);
            }
        }
        #pragma unroll
        for (int ks = 0; ks < 4; ++ks) {
            const bf16x8 av = *(const bf16x8*)&acc_[(mtk * 16 + l15) * 136 + ks * 32 + quad * 8];
            const bf16x8 bv = *(const bf16x8*)&xcc[(ntc * 16 + l15) * 136 + ks * 32 + quad * 8];
            acc = __builtin_amdgcn_mfma_f32_16x16x32_bf16(av, bv, acc, 0, 0, 0);
        }
        __syncthreads();
    }
    *(float4*)&partv[(size_t)b * 1024 + t * 4] =
        make_float4(acc[0], acc[1], acc[2], acc[3]);
}
__global__ __launch_bounds__(256) void k_vlad(const void* __restrict__ x,
                                              const us* __restrict__ attn_g,
                                              const int* __restrict__ flag,
                                              float* __restrict__ partv) {
    __shared__ __align__(16) us sm[4 * 4352];
    if (*flag) vlad_body<float>((const float*)x, attn_g, partv, sm);
    else       vlad_body<us>((const us*)x, attn_g, partv, sm);
}

// ---------------------------------------------------------------------------
// K4 (k_vfin): grid 512 = n*32 + ct. Combine p-halves, -asum*cent, store vlad
// fp32, per-(n,k) ssq atomics.
// ---------------------------------------------------------------------------
template <typename T>
__device__ __forceinline__ void vfin_body(const float* __restrict__ partv,
                                          const T* __restrict__ cent,
                                          const float* __restrict__ asum,
                                          float* __restrict__ vlad,
                                          float* __restrict__ ssqnk) {
    const int s = blockIdx.x, t = threadIdx.x;
    const int n = s >> 5, ct = s & 31, cb = ct * 32;
    const int b0 = n * 64 + ct * 2, b1 = b0 + 1;
    const float4 f0 = *(const float4*)&partv[(size_t)b0 * 1024 + t * 4];
    const float4 f1 = *(const float4*)&partv[(size_t)b1 * 1024 + t * 4];
    const int lane = t & 63, wv = t >> 6;
    const int quad = lane >> 4, l15 = lane & 15;
    const int mtk = wv >> 1, ntc = wv & 1;
    const int cg = cb + ntc * 16 + l15;
    const float vals[4] = {f0.x + f1.x, f0.y + f1.y, f0.z + f1.z, f0.w + f1.w};
    #pragma unroll
    for (int reg = 0; reg < 4; ++reg) {
        const int k = mtk * 16 + quad * 4 + reg;
        const float A = asum[n * KK + k];
        const float v = vals[reg] - A * IO<T>::ld(&cent[k * CC + cg]);
        vlad[((size_t)n * KK + k) * CC + cg] = v;
        float s2 = v * v;
        s2 += __shfl_xor(s2, 1, 64);
        s2 += __shfl_xor(s2, 2, 64);
        s2 += __shfl_xor(s2, 4, 64);
        s2 += __shfl_xor(s2, 8, 64);
        if (l15 == 0) atomicAdd(&ssqnk[n * KK + k], s2);
    }
}
__global__ __launch_bounds__(256) void k_vfin(const float* __restrict__ partv,
                                              const void* __restrict__ cent,
                                              const int* __restrict__ flag,
                                              const float* __restrict__ asum,
                                              float* __restrict__ vlad,
                                              float* __restrict__ ssqnk) {
    if (*flag) vfin_body<float>(partv, (const float*)cent, asum, vlad, ssqnk);
    else       vfin_body<us>(partv, (const us*)cent, asum, vlad, ssqnk);
}

// ---------------------------------------------------------------------------
// K5: per (n,k) intra rnorm; per n global rnorm (sum_k ssq_k * r_k^2).
// ---------------------------------------------------------------------------
__global__ __launch_bounds__(64) void k_factors(const float* __restrict__ ssqnk,
                                                float* __restrict__ rintra,
                                                float* __restrict__ rglob) {
    const int n = blockIdx.x, t = threadIdx.x;
    const float s = (t < KK) ? ssqnk[n * KK + t] : 0.f;
    const float r = 1.0f / fmaxf(sqrtf(s), EPSF);
    if (t < KK) rintra[n * KK + t] = r;
    float g = s * r * r;
    for (int off = 32; off > 0; off >>= 1) g += __shfl_down(g, off, 64);
    if (t == 0) rglob[n] = 1.0f / fmaxf(sqrtf(g), EPSF);
}

// ---------------------------------------------------------------------------
// K6: out = vlad * rintra * rglob. grid N*K, 256 thr (float4 per thread).
// ---------------------------------------------------------------------------
__global__ __launch_bounds__(256) void k_out(const float* __restrict__ vlad,
                                             const float* __restrict__ rintra,
                                             const float* __restrict__ rglob,
                                             const int* __restrict__ flag,
                                             void* __restrict__ out) {
    const int b = blockIdx.x, t = threadIdx.x;
    const float f = rintra[b] * rglob[b >> 5];
    const float4 v = ((const float4*)(vlad + (size_t)b * CC))[t];
    if (*flag) {
        float4 o; o.x = v.x * f; o.y = v.y * f; o.z = v.z * f; o.w = v.w * f;
        ((float4*)((float*)out + (size_t)b * CC))[t] = o;
    } else {
        ushort4 u;
        u.x = f2bf(v.x * f); u.y = f2bf(v.y * f);
        u.z = f2bf(v.z * f); u.w = f2bf(v.w * f);
        ((ushort4*)((us*)out + (size_t)b * CC))[t] = u;
    }
}

extern "C" void kernel_launch(void* const* d_in, const int* in_sizes, int n_in,
                              void* d_out, int out_size, void* d_ws, size_t ws_size,
                              hipStream_t stream) {
    const void* x    = d_in[0];
    const void* w    = d_in[1];
    const void* cent = d_in[2];

    float* ws     = (float*)d_ws;
    float* vlad   = ws;                       // 524288 f
    float* asum   = vlad + 524288;            // 512 f
    float* ssqnk  = asum + 512;               // 512 f
    float* rintra = ssqnk + 512;              // 512 f
    float* rglob  = rintra + 512;             // 16 f
    int*   flag   = (int*)(rglob + 16);       // 4 i
    float* part_a = (float*)(flag + 4);       // 1024*1024 f (attn partials)
    float* ssp    = part_a + 1024 * 1024;     // 1024*32 f
    float* part_v = ssp + 1024 * 32;          // 1024*1024 f (vlad partials)
    us* attn_g = (us*)(part_v + 1024 * 1024); // 524288 us (a~ = a*rn)
    us* wbf    = attn_g + 524288;             // 32768 us

    hipMemsetAsync(asum, 0, 2 * 512 * sizeof(float), stream);  // asum+ssqnk

    k_prep<<<16, 256, 0, stream>>>((const us*)x, w, flag, wbf);
    k_attn<<<1024, 256, 0, stream>>>(x, wbf, flag, part_a, ssp);
    k_soft<<<512, 256, 0, stream>>>(part_a, ssp, attn_g, asum);
    k_vlad<<<1024, 256, 0, stream>>>(x, attn_g, flag, part_v);
    k_vfin<<<512, 256, 0, stream>>>(part_v, cent, flag, asum, vlad, ssqnk);
    k_factors<<<NB, 64, 0, stream>>>(ssqnk, rintra, rglob);
    k_out<<<NB * KK, 256, 0, stream>>>(vlad, rintra, rglob, flag, d_out);
}